// Round 1
// baseline (244.761 us; speedup 1.0000x reference)
//
#include <hip/hip_runtime.h>
#include <hip/hip_bf16.h>
#include <cstdint>
#include <cstddef>

// LSTMCell: gates = [input|hx] @ [Wih|Whh]^T + b_ih + b_hh  (4096 x 4096 x K=2048)
// Strategy: split-bf16 (hi+lo) 3-product MFMA GEMM (fp32-accurate), fused LSTM epilogue.
// Round 1: m97-style single-buffer global_load_lds staging, BK=32, 128x(4x64) tile.

#define B_ROWS 4096
#define HDIM   1024
#define KDIM   2048
#define BM     128
#define HB     64
#define BK     32
#define KSTEPS (KDIM / BK)

typedef unsigned short u16;
using f32x4  = __attribute__((ext_vector_type(4))) float;
using short8 = __attribute__((ext_vector_type(8))) short;

__device__ __forceinline__ u16 f2bf(float f) {
    unsigned int u = __builtin_bit_cast(unsigned int, f);
    u += 0x7FFFu + ((u >> 16) & 1u);
    return (u16)(u >> 16);
}
__device__ __forceinline__ float bf2f(u16 s) {
    unsigned int u = ((unsigned int)s) << 16;
    return __builtin_bit_cast(float, u);
}

// ---------------- pack: f32 -> bf16 hi/lo, concat K-dim ----------------
__global__ void pack_kernel(const float* __restrict__ input, const float* __restrict__ hx,
                            const float* __restrict__ wih, const float* __restrict__ whh,
                            u16* __restrict__ Ah, u16* __restrict__ Al,
                            u16* __restrict__ Wh, u16* __restrict__ Wl)
{
    const int PER = (B_ROWS * KDIM) / 4;  // float4 groups per matrix
    int stride = gridDim.x * blockDim.x;
    for (int i = blockIdx.x * blockDim.x + threadIdx.x; i < 2 * PER; i += stride) {
        int isW = (i >= PER) ? 1 : 0;
        int e = i - isW * PER;
        int row = e >> 9;            // 512 groups per row of 2048
        int k = (e & 511) << 2;
        const float* s0 = isW ? wih : input;
        const float* s1 = isW ? whh : hx;
        const float* src = (k < 1024) ? (s0 + (size_t)row * 1024 + k)
                                      : (s1 + (size_t)row * 1024 + (k - 1024));
        float4 v = *(const float4*)src;
        u16 h0 = f2bf(v.x), h1 = f2bf(v.y), h2 = f2bf(v.z), h3 = f2bf(v.w);
        u16 l0 = f2bf(v.x - bf2f(h0));
        u16 l1 = f2bf(v.y - bf2f(h1));
        u16 l2 = f2bf(v.z - bf2f(h2));
        u16 l3 = f2bf(v.w - bf2f(h3));
        size_t doff = (size_t)row * KDIM + k;
        u16* dh = (isW ? Wh : Ah) + doff;
        u16* dl = (isW ? Wl : Al) + doff;
        *(ushort4*)dh = make_ushort4(h0, h1, h2, h3);
        *(ushort4*)dl = make_ushort4(l0, l1, l2, l3);
    }
}

// ---------------- fused GEMM + LSTM epilogue ----------------
__device__ __forceinline__ void gload16(const void* g, void* l) {
    __builtin_amdgcn_global_load_lds((const __attribute__((address_space(1))) void*)g,
                                     (__attribute__((address_space(3))) void*)l, 16, 0, 0);
}
__device__ __forceinline__ float sigmf(float x) { return 1.0f / (1.0f + __expf(-x)); }
__device__ __forceinline__ float tanhfast(float x) { return 1.0f - 2.0f / (1.0f + __expf(2.0f * x)); }

__launch_bounds__(256, 2)
__global__ void lstm_fused(const u16* __restrict__ Ah, const u16* __restrict__ Al,
                           const u16* __restrict__ Wh, const u16* __restrict__ Wl,
                           const float* __restrict__ cx, const float* __restrict__ eps_c,
                           const float* __restrict__ eps_h,
                           const float* __restrict__ bias_ih, const float* __restrict__ bias_hh,
                           const float* __restrict__ noise_q, const float* __restrict__ noise_e,
                           float* __restrict__ out)
{
    // LDS: [hi/lo][kchunk(8 bf16)][row][8]  — linear for global_load_lds, conflict-free b128 reads
    __shared__ __align__(16) u16 lA[2][4][BM][8];     // 16 KB
    __shared__ __align__(16) u16 lW[2][4][256][8];    // 32 KB

    const int nwg = 512;
    int bid = blockIdx.x;
    // XCD-bijective swizzle (512 % 8 == 0): consecutive w share the same W panel -> L2 reuse
    int w = (bid & 7) * (nwg >> 3) + (bid >> 3);
    int mi = w & 31;          // 32 M-chunks of 128 rows
    int hi = w >> 5;          // 16 h-chunks of 64 cols
    int bm0 = mi * BM;
    int h0 = hi * HB;

    int tid  = threadIdx.x;
    int lane = tid & 63;
    int wv   = tid >> 6;      // wave id 0..3, also the k-chunk this wave stages
    int wm   = wv & 1;        // M half (64 rows)
    int wh   = wv >> 1;       // h half (32 cols)

    // staging global offsets (elements); wave wv stages k-chunk panel wv (elems wv*8..wv*8+7)
    size_t aoff0 = (size_t)(bm0 + lane) * KDIM + wv * 8;
    size_t aoff1 = (size_t)(bm0 + 64 + lane) * KDIM + wv * 8;
    size_t woff[4];
#pragma unroll
    for (int q = 0; q < 4; ++q)
        woff[q] = (size_t)(q * 1024 + h0 + lane) * KDIM + wv * 8;  // gate q, h = h0+lane

    f32x4 acc[4][8];   // [m-frag][gate*2+hh]
#pragma unroll
    for (int m = 0; m < 4; ++m)
#pragma unroll
        for (int n = 0; n < 8; ++n)
            acc[m][n] = (f32x4){0.f, 0.f, 0.f, 0.f};

    const int c  = lane >> 4;   // fragment k-chunk
    const int rl = lane & 15;

    const u16* pA0 = &lA[0][c][wm * 64 + rl][0];
    const u16* pA1 = &lA[1][c][wm * 64 + rl][0];
    const u16* pW0 = &lW[0][c][wh * 32 + rl][0];
    const u16* pW1 = &lW[1][c][wh * 32 + rl][0];

#pragma unroll 1
    for (int kt = 0; kt < KSTEPS; ++kt) {
        size_t kk = (size_t)kt * BK;
        // ---- stage 48 KB: 12 x global_load_lds_dwordx4 per thread-slot ----
        gload16(Ah + aoff0 + kk, &lA[0][wv][0][0]);
        gload16(Ah + aoff1 + kk, &lA[0][wv][64][0]);
        gload16(Al + aoff0 + kk, &lA[1][wv][0][0]);
        gload16(Al + aoff1 + kk, &lA[1][wv][64][0]);
#pragma unroll
        for (int q = 0; q < 4; ++q) {
            gload16(Wh + woff[q] + kk, &lW[0][wv][q * 64][0]);
            gload16(Wl + woff[q] + kk, &lW[1][wv][q * 64][0]);
        }
        __syncthreads();   // compiler drains vmcnt before s_barrier

        short8 a_h[4], a_l[4];
#pragma unroll
        for (int m = 0; m < 4; ++m) {
            a_h[m] = *(const short8*)(pA0 + m * 16 * 8);
            a_l[m] = *(const short8*)(pA1 + m * 16 * 8);
        }
#pragma unroll
        for (int g = 0; g < 4; ++g) {
#pragma unroll
            for (int hhf = 0; hhf < 2; ++hhf) {
                short8 w_h = *(const short8*)(pW0 + (g * 64 + hhf * 16) * 8);
                short8 w_l = *(const short8*)(pW1 + (g * 64 + hhf * 16) * 8);
                int nf = g * 2 + hhf;
#pragma unroll
                for (int m = 0; m < 4; ++m) {
                    acc[m][nf] = __builtin_amdgcn_mfma_f32_16x16x32_bf16(a_h[m], w_h, acc[m][nf], 0, 0, 0);
                    acc[m][nf] = __builtin_amdgcn_mfma_f32_16x16x32_bf16(a_l[m], w_h, acc[m][nf], 0, 0, 0);
                    acc[m][nf] = __builtin_amdgcn_mfma_f32_16x16x32_bf16(a_h[m], w_l, acc[m][nf], 0, 0, 0);
                }
            }
        }
        __syncthreads();
    }

    // ---- epilogue: all 4 gates for (r,h) are lane-local ----
    float sq_e = sqrtf(noise_e[0]);
    float sq_q = sqrtf(noise_q[0]);
    int hbase = h0 + wh * 32 + rl;
#pragma unroll
    for (int hhf = 0; hhf < 2; ++hhf) {
        int h = hbase + hhf * 16;
        float bsum[4];
#pragma unroll
        for (int g = 0; g < 4; ++g)
            bsum[g] = bias_ih[g * 1024 + h] + bias_hh[g * 1024 + h];
#pragma unroll
        for (int m = 0; m < 4; ++m) {
            int r0 = bm0 + wm * 64 + m * 16 + (lane >> 4) * 4;
#pragma unroll
            for (int j = 0; j < 4; ++j) {
                int r = r0 + j;
                float gi = acc[m][0 + hhf][j] + bsum[0];
                float gf = acc[m][2 + hhf][j] + bsum[1];
                float gc = acc[m][4 + hhf][j] + bsum[2];
                float go = acc[m][6 + hhf][j] + bsum[3];
                float ig = sigmf(gi), fg = sigmf(gf);
                float cg = tanhfast(gc), og = sigmf(go);
                size_t off = (size_t)r * HDIM + h;
                float cyv = fg * cx[off] + ig * cg + sq_e * eps_c[off];
                float hyv = og * tanhfast(cyv) + sq_q * eps_h[off];
                out[off] = hyv;                                // hy
                out[(size_t)B_ROWS * HDIM + off] = cyv;        // cy
            }
        }
    }
}

extern "C" void kernel_launch(void* const* d_in, const int* in_sizes, int n_in,
                              void* d_out, int out_size, void* d_ws, size_t ws_size,
                              hipStream_t stream)
{
    const float* input = (const float*)d_in[0];
    const float* hx    = (const float*)d_in[1];
    const float* cx    = (const float*)d_in[2];
    const float* nq    = (const float*)d_in[3];
    const float* ne    = (const float*)d_in[4];
    const float* wih   = (const float*)d_in[5];
    const float* whh   = (const float*)d_in[6];
    const float* bih   = (const float*)d_in[7];
    const float* bhh   = (const float*)d_in[8];
    const float* epsc  = (const float*)d_in[9];
    const float* epsh  = (const float*)d_in[10];
    float* out = (float*)d_out;

    u16* Ah = (u16*)d_ws;
    u16* Al = Ah + (size_t)B_ROWS * KDIM;
    u16* Wh = Al + (size_t)B_ROWS * KDIM;
    u16* Wl = Wh + (size_t)B_ROWS * KDIM;   // total 64 MB of ws

    hipLaunchKernelGGL(pack_kernel, dim3(2048), dim3(256), 0, stream,
                       input, hx, wih, whh, Ah, Al, Wh, Wl);
    hipLaunchKernelGGL(lstm_fused, dim3(512), dim3(256), 0, stream,
                       Ah, Al, Wh, Wl, cx, epsc, epsh, bih, bhh, nq, ne, out);
}